// Round 1
// baseline (656.899 us; speedup 1.0000x reference)
//
#include <hip/hip_runtime.h>

typedef unsigned short u16;
typedef unsigned int u32;
typedef __attribute__((ext_vector_type(8))) __bf16 bf16x8;
typedef __attribute__((ext_vector_type(4))) float f32x4;

#define T_TOK 8192
#define DMODEL 2048
#define N_EXP 8

// ---------- helpers ----------
__device__ __forceinline__ u32 f2bf_bits(float f) {
    u32 u = __builtin_bit_cast(u32, f);
    return (u + 0x7fffu + ((u >> 16) & 1u)) >> 16;   // RNE truncate to bf16
}
__device__ __forceinline__ u32 pack2(float a, float b) {
    return f2bf_bits(a) | (f2bf_bits(b) << 16);
}

__device__ __forceinline__ void load_lds16(const u16* g, u16* l) {
    void* gnc = (void*)g;  // drop const, then addrspace-cast
    __builtin_amdgcn_global_load_lds(
        (__attribute__((address_space(1))) void*)gnc,
        (__attribute__((address_space(3))) void*)l,
        16, 0, 0);
}

// ---------- kernel 0: zero the counters (counts[8] + sum_topp[8]) ----------
__global__ void zero_kernel(u32* p) {
    if (threadIdx.x < 16) p[threadIdx.x] = 0u;
}

// ---------- kernel 1: W fp32 -> bf16 ----------
__global__ void __launch_bounds__(256) convert_w_kernel(const float* __restrict__ W,
                                                        u16* __restrict__ Wb) {
    size_t i = ((size_t)blockIdx.x * 256 + threadIdx.x) * 8;
    float4 a = *(const float4*)(W + i);
    float4 b = *(const float4*)(W + i + 4);
    uint4 o;
    o.x = pack2(a.x, a.y);
    o.y = pack2(a.z, a.w);
    o.z = pack2(b.x, b.y);
    o.w = pack2(b.z, b.w);
    *(uint4*)(Wb + i) = o;
}

// ---------- kernel 2: router (logits fp32, softmax/argmax, compaction, x->bf16) ----------
__global__ void __launch_bounds__(256) router_kernel(const float* __restrict__ x,
                                                     const float* __restrict__ Wr,
                                                     const float* __restrict__ br,
                                                     u16* __restrict__ xb,
                                                     int* __restrict__ perm,
                                                     float* __restrict__ topp,
                                                     int* __restrict__ counts,
                                                     float* __restrict__ sumt) {
    __shared__ __align__(16) float sWr[N_EXP * DMODEL];   // 64 KB
    int tid = threadIdx.x;
    for (int i = tid; i < N_EXP * DMODEL; i += 256) sWr[i] = Wr[i];
    __syncthreads();

    int lane = tid & 63;
    int w = tid >> 6;
    int tbase = blockIdx.x * 32 + w * 8;   // 4 waves * 8 tokens = 32 tokens/block

    for (int j = 0; j < 8; j++) {
        int t = tbase + j;
        const float4* xp = (const float4*)(x + ((size_t)t << 11));
        u16* xbp = xb + ((size_t)t << 11);

        float acc[8];
#pragma unroll
        for (int e = 0; e < 8; e++) acc[e] = 0.0f;

#pragma unroll
        for (int i = 0; i < 8; i++) {
            int vidx = i * 64 + lane;           // float4 index within the row
            float4 xv = xp[vidx];
            uint2 pk;
            pk.x = pack2(xv.x, xv.y);
            pk.y = pack2(xv.z, xv.w);
            *(uint2*)(xbp + (size_t)vidx * 4) = pk;   // fused x -> bf16
#pragma unroll
            for (int e = 0; e < 8; e++) {
                float4 wv = *(const float4*)&sWr[e * DMODEL + vidx * 4];
                acc[e] = fmaf(xv.x, wv.x, fmaf(xv.y, wv.y,
                          fmaf(xv.z, wv.z, fmaf(xv.w, wv.w, acc[e]))));
            }
        }
        // butterfly reduce all 8 dots across the 64-lane wave
#pragma unroll
        for (int off = 32; off; off >>= 1)
#pragma unroll
            for (int e = 0; e < 8; e++)
                acc[e] += __shfl_xor(acc[e], off, 64);

        if (lane == 0) {
            float lg[8];
#pragma unroll
            for (int e = 0; e < 8; e++) lg[e] = acc[e] + br[e];
            float m = lg[0];
            int am = 0;
#pragma unroll
            for (int e = 1; e < 8; e++)
                if (lg[e] > m) { m = lg[e]; am = e; }
            float s = 0.0f;
#pragma unroll
            for (int e = 0; e < 8; e++) s += __expf(lg[e] - m);
            float tp = 1.0f / s;               // = exp(max-max)/sumexp

            int pos = atomicAdd(&counts[am], 1);
            perm[(am << 13) + pos] = t;
            topp[t] = tp;
            atomicAdd(&sumt[am], tp);
        }
    }
}

// ---------- kernel 3: grouped GEMM  y[t] = (x_bf16[t] . W[e]^T + b[e]) * topp[t] ----------
// grid: 8 experts * 64 tile-rows * 16 col-tiles = 8192 blocks; early-exit on empty tiles.
__global__ void __launch_bounds__(256) moe_gemm_kernel(const u16* __restrict__ xb,
                                                       const u16* __restrict__ Wb,
                                                       const float* __restrict__ bias,
                                                       const int* __restrict__ perm,
                                                       const int* __restrict__ counts,
                                                       const float* __restrict__ topp,
                                                       float* __restrict__ out) {
    __shared__ __align__(16) u16 ldsA[4096];   // 128 rows x 32 k, chunk-major, 8 KB
    __shared__ __align__(16) u16 ldsB[4096];

    int bid = blockIdx.x;
    int e  = bid >> 10;
    int tr = (bid >> 4) & 63;
    int tc = bid & 15;
    int cnt = counts[e];
    int row0 = tr << 7;
    if (row0 >= cnt) return;                   // block-uniform exit
    int n0 = tc << 7;

    int tid = threadIdx.x;
    int lane = tid & 63;
    int w = tid >> 6;

    // staging: 512 slots of 16B per tile; slot = kchunk*128 + row (chunk-major)
    int s0 = tid, s1 = tid + 256;
    int r0 = s0 & 127, c0 = s0 >> 7;
    int r1 = s1 & 127, c1 = s1 >> 7;

    const int* permE = perm + (e << 13);
    int ta0 = permE[min(row0 + r0, cnt - 1)];
    int ta1 = permE[min(row0 + r1, cnt - 1)];
    const u16* gA0 = xb + ((size_t)ta0 << 11) + (c0 << 3);
    const u16* gA1 = xb + ((size_t)ta1 << 11) + (c1 << 3);
    const u16* WbE = Wb + ((size_t)e << 22);
    const u16* gB0 = WbE + ((size_t)(n0 + r0) << 11) + (c0 << 3);
    const u16* gB1 = WbE + ((size_t)(n0 + r1) << 11) + (c1 << 3);
    u16* lA0 = ldsA + s0 * 8;
    u16* lA1 = ldsA + s1 * 8;
    u16* lB0 = ldsB + s0 * 8;
    u16* lB1 = ldsB + s1 * 8;

    // wave tiling: 2x2 waves of 64x64, each 4x4 grid of 16x16x32 MFMA
    int mbase = (w & 1) << 6;
    int nbase = (w >> 1) << 6;
    int mrow = lane & 15;
    int kch = lane >> 4;                       // A/B operand k-chunk = lane>>4
    const u16* aAddr = ldsA + (kch * 128 + mbase + mrow) * 8;
    const u16* bAddr = ldsB + (kch * 128 + nbase + mrow) * 8;

    f32x4 acc[4][4];
#pragma unroll
    for (int mi = 0; mi < 4; mi++)
#pragma unroll
        for (int ni = 0; ni < 4; ni++)
            acc[mi][ni] = (f32x4){0.0f, 0.0f, 0.0f, 0.0f};

    for (int kt = 0; kt < DMODEL / 32; kt++) {
        int ko = kt << 5;
        load_lds16(gA0 + ko, lA0);
        load_lds16(gA1 + ko, lA1);
        load_lds16(gB0 + ko, lB0);
        load_lds16(gB1 + ko, lB1);
        __syncthreads();                        // drains vmcnt -> LDS writes visible

        bf16x8 af[4], bf[4];
#pragma unroll
        for (int i = 0; i < 4; i++) {
            af[i] = *(const bf16x8*)(aAddr + i * 128);   // +16 rows per fragment
            bf[i] = *(const bf16x8*)(bAddr + i * 128);
        }
#pragma unroll
        for (int mi = 0; mi < 4; mi++)
#pragma unroll
            for (int ni = 0; ni < 4; ni++)
                acc[mi][ni] = __builtin_amdgcn_mfma_f32_16x16x32_bf16(
                    af[mi], bf[ni], acc[mi][ni], 0, 0, 0);
        __syncthreads();                        // protect LDS before next staging
    }

    // epilogue: C/D layout col = lane&15 (n), row = (lane>>4)*4 + reg (m)
    const float* bE = bias + (e << 11);
    float bv[4];
#pragma unroll
    for (int ni = 0; ni < 4; ni++)
        bv[ni] = bE[n0 + nbase + ni * 16 + (lane & 15)];

    int rb = row0 + mbase + ((lane >> 4) << 2);
#pragma unroll
    for (int mi = 0; mi < 4; mi++) {
        int t_[4]; float tp_[4]; int v_[4];
#pragma unroll
        for (int r = 0; r < 4; r++) {
            int gr = rb + mi * 16 + r;
            v_[r] = gr < cnt;
            int grc = v_[r] ? gr : (cnt - 1);
            t_[r] = permE[grc];
            tp_[r] = topp[t_[r]];
        }
#pragma unroll
        for (int ni = 0; ni < 4; ni++) {
            int col = n0 + nbase + ni * 16 + (lane & 15);
            f32x4 v = acc[mi][ni];
#pragma unroll
            for (int r = 0; r < 4; r++) {
                if (v_[r])
                    out[((size_t)t_[r] << 11) + col] = (v[r] + bv[ni]) * tp_[r];
            }
        }
    }
}

// ---------- kernel 4: aux loss ----------
__global__ void loss_kernel(const int* __restrict__ counts,
                            const float* __restrict__ sumt,
                            float* __restrict__ lossOut) {
    if (threadIdx.x == 0) {
        float acc = 0.0f;
        for (int e = 0; e < 8; e++) {
            float frac = (float)counts[e] / 8192.0f;
            float prob = sumt[e] / (8192.0f * 8192.0f);
            acc = fmaf(frac, prob, acc);
        }
        lossOut[0] = acc * 3e-6f * 8.0f;
    }
}

extern "C" void kernel_launch(void* const* d_in, const int* in_sizes, int n_in,
                              void* d_out, int out_size, void* d_ws, size_t ws_size,
                              hipStream_t stream) {
    const float* x  = (const float*)d_in[0];   // (4,2048,2048)
    const float* Wr = (const float*)d_in[1];   // (8,2048)
    const float* br = (const float*)d_in[2];   // (8,)
    const float* W  = (const float*)d_in[3];   // (8,2048,2048)
    const float* b  = (const float*)d_in[4];   // (8,2048)
    float* out = (float*)d_out;                // 16777216 y + 1 loss

    char* ws = (char*)d_ws;
    u16* Wb     = (u16*)ws;                      // 67,108,864 B
    u16* xb     = (u16*)(ws + 67108864);         // 33,554,432 B
    int* perm   = (int*)(ws + 100663296);        //    262,144 B (8 experts x 8192)
    float* topp = (float*)(ws + 100925440);      //     32,768 B
    int* counts = (int*)(ws + 100958208);        //         32 B
    float* sumt = (float*)(ws + 100958240);      //         32 B

    zero_kernel<<<1, 64, 0, stream>>>((u32*)counts);   // counts[8] + sumt[8] contiguous
    convert_w_kernel<<<(8 * 2048 * 2048) / (256 * 8), 256, 0, stream>>>(W, Wb);
    router_kernel<<<T_TOK / 32, 256, 0, stream>>>(x, Wr, br, xb, perm, topp, counts, sumt);
    moe_gemm_kernel<<<N_EXP * 64 * 16, 256, 0, stream>>>(xb, Wb, b, perm, counts, topp, out);
    loss_kernel<<<1, 64, 0, stream>>>(counts, sumt, out + (size_t)T_TOK * DMODEL);
}

// Round 2
// 489.972 us; speedup vs baseline: 1.3407x; 1.3407x over previous
//
#include <hip/hip_runtime.h>

typedef unsigned short u16;
typedef unsigned int u32;
typedef __attribute__((ext_vector_type(8))) __bf16 bf16x8;
typedef __attribute__((ext_vector_type(4))) float f32x4;

#define T_TOK 8192
#define DMODEL 2048
#define N_EXP 8
// counters padded: counts[e] at counts[e*16] (64 B apart), same for sumt

// ---------- helpers ----------
__device__ __forceinline__ u32 f2bf_bits(float f) {
    u32 u = __builtin_bit_cast(u32, f);
    return (u + 0x7fffu + ((u >> 16) & 1u)) >> 16;   // RNE truncate to bf16
}
__device__ __forceinline__ u32 pack2(float a, float b) {
    return f2bf_bits(a) | (f2bf_bits(b) << 16);
}

__device__ __forceinline__ void load_lds16(const u16* g, u16* l) {
    void* gnc = (void*)g;
    __builtin_amdgcn_global_load_lds(
        (__attribute__((address_space(1))) void*)gnc,
        (__attribute__((address_space(3))) void*)l,
        16, 0, 0);
}

// ---------- kernel 0: zero padded counters (counts 512B + sumt 512B) ----------
__global__ void zero_kernel(u32* p) {
    p[threadIdx.x] = 0u;   // 256 threads x 4B = 1024 B
}

// ---------- kernel 1: W fp32 -> bf16 ----------
__global__ void __launch_bounds__(256) convert_w_kernel(const float* __restrict__ W,
                                                        u16* __restrict__ Wb) {
    size_t i = ((size_t)blockIdx.x * 256 + threadIdx.x) * 8;
    float4 a = *(const float4*)(W + i);
    float4 b = *(const float4*)(W + i + 4);
    uint4 o;
    o.x = pack2(a.x, a.y);
    o.y = pack2(a.z, a.w);
    o.z = pack2(b.x, b.y);
    o.w = pack2(b.z, b.w);
    *(uint4*)(Wb + i) = o;
}

// ---------- kernel 2: router — 1 token/wave, 2048 blocks, no big LDS ----------
__global__ void __launch_bounds__(256) router_kernel(const float* __restrict__ x,
                                                     const float* __restrict__ Wr,
                                                     const float* __restrict__ br,
                                                     u16* __restrict__ xb,
                                                     int* __restrict__ perm,
                                                     float* __restrict__ topp,
                                                     int* __restrict__ counts,
                                                     float* __restrict__ sumt) {
    __shared__ int sEid[4];
    __shared__ float sTp[4];

    int tid = threadIdx.x;
    int lane = tid & 63;
    int w = tid >> 6;
    int t = blockIdx.x * 4 + w;

    const float4* xp = (const float4*)(x + ((size_t)t << 11));
    u16* xbp = xb + ((size_t)t << 11);

    float acc[8];
#pragma unroll
    for (int e = 0; e < 8; e++) acc[e] = 0.0f;

#pragma unroll
    for (int i = 0; i < 8; i++) {
        int vidx = i * 64 + lane;               // float4 index within the row
        float4 xv = xp[vidx];
        uint2 pk;
        pk.x = pack2(xv.x, xv.y);
        pk.y = pack2(xv.z, xv.w);
        *(uint2*)(xbp + (size_t)vidx * 4) = pk; // fused x -> bf16
#pragma unroll
        for (int e = 0; e < 8; e++) {
            float4 wv = *(const float4*)(Wr + e * DMODEL + vidx * 4);  // L2-resident
            acc[e] = fmaf(xv.x, wv.x, fmaf(xv.y, wv.y,
                      fmaf(xv.z, wv.z, fmaf(xv.w, wv.w, acc[e]))));
        }
    }
#pragma unroll
    for (int off = 32; off; off >>= 1)
#pragma unroll
        for (int e = 0; e < 8; e++)
            acc[e] += __shfl_xor(acc[e], off, 64);

    if (lane == 0) {
        float lg[8];
#pragma unroll
        for (int e = 0; e < 8; e++) lg[e] = acc[e] + br[e];
        float m = lg[0];
        int am = 0;
#pragma unroll
        for (int e = 1; e < 8; e++)
            if (lg[e] > m) { m = lg[e]; am = e; }
        float s = 0.0f;
#pragma unroll
        for (int e = 0; e < 8; e++) s += __expf(lg[e] - m);
        float tp = 1.0f / s;
        sEid[w] = am;
        sTp[w] = tp;
        topp[t] = tp;
    }
    __syncthreads();
    if (tid < 4) {
        int e = sEid[tid];
        float tp = sTp[tid];
        int pos = atomicAdd(&counts[e * 16], 1);          // padded: 8 separate lines
        perm[(e << 13) + pos] = blockIdx.x * 4 + tid;
        atomicAdd(&sumt[e * 16], tp);
    }
}

// ---------- kernel 3: grouped GEMM, BK=64 ----------
// bid = tr*128 + e*16 + tc  -> active blocks are a contiguous prefix
__global__ void __launch_bounds__(256) moe_gemm_kernel(const u16* __restrict__ xb,
                                                       const u16* __restrict__ Wb,
                                                       const float* __restrict__ bias,
                                                       const int* __restrict__ perm,
                                                       const int* __restrict__ counts,
                                                       const float* __restrict__ topp,
                                                       float* __restrict__ out) {
    __shared__ __align__(16) u16 ldsA[8192];   // 128 rows x 64 k, chunk-major, 16 KB
    __shared__ __align__(16) u16 ldsB[8192];

    int bid = blockIdx.x;
    int tr = bid >> 7;
    int e  = (bid >> 4) & 7;
    int tc = bid & 15;
    int cnt = counts[e * 16];
    int row0 = tr << 7;
    if (row0 >= cnt) return;
    int n0 = tc << 7;

    int tid = threadIdx.x;
    int lane = tid & 63;
    int w = tid >> 6;

    // staging: 1024 slots of 16B per matrix; slot = kchunk*128 + row, kchunk 0..7
    const int* permE = perm + (e << 13);
    const u16* WbE = Wb + ((size_t)e << 22);
    const u16* gA[4]; u16* lA[4];
    const u16* gB[4]; u16* lB[4];
#pragma unroll
    for (int j = 0; j < 4; j++) {
        int s = tid + j * 256;
        int r = s & 127, c = s >> 7;
        int ta = permE[min(row0 + r, cnt - 1)];
        gA[j] = xb + ((size_t)ta << 11) + (c << 3);
        gB[j] = WbE + ((size_t)(n0 + r) << 11) + (c << 3);
        lA[j] = ldsA + s * 8;
        lB[j] = ldsB + s * 8;
    }

    // wave tiling: 2x2 waves of 64x64, each 4x4 grid of 16x16x32 MFMA
    int mbase = (w & 1) << 6;
    int nbase = (w >> 1) << 6;
    int mrow = lane & 15;
    int kq = lane >> 4;                         // 8-elem chunk within a 32-k subtile
    int aOff = (kq * 128 + mbase + mrow) * 8;   // u16 offset
    int bOff = (kq * 128 + nbase + mrow) * 8;

    f32x4 acc[4][4];
#pragma unroll
    for (int mi = 0; mi < 4; mi++)
#pragma unroll
        for (int ni = 0; ni < 4; ni++)
            acc[mi][ni] = (f32x4){0.0f, 0.0f, 0.0f, 0.0f};

    for (int kt = 0; kt < DMODEL / 64; kt++) {
        int ko = kt << 6;
#pragma unroll
        for (int j = 0; j < 4; j++) load_lds16(gA[j] + ko, lA[j]);
#pragma unroll
        for (int j = 0; j < 4; j++) load_lds16(gB[j] + ko, lB[j]);
        __syncthreads();

#pragma unroll
        for (int ks = 0; ks < 2; ks++) {
            bf16x8 af[4], bf[4];
#pragma unroll
            for (int i = 0; i < 4; i++) {
                af[i] = *(const bf16x8*)(ldsA + aOff + (ks * 512 + i * 16) * 8);
                bf[i] = *(const bf16x8*)(ldsB + bOff + (ks * 512 + i * 16) * 8);
            }
#pragma unroll
            for (int mi = 0; mi < 4; mi++)
#pragma unroll
                for (int ni = 0; ni < 4; ni++)
                    acc[mi][ni] = __builtin_amdgcn_mfma_f32_16x16x32_bf16(
                        af[mi], bf[ni], acc[mi][ni], 0, 0, 0);
        }
        __syncthreads();
    }

    // epilogue: C/D layout col = lane&15 (n), row = (lane>>4)*4 + reg (m)
    const float* bE = bias + (e << 11);
    float bv[4];
#pragma unroll
    for (int ni = 0; ni < 4; ni++)
        bv[ni] = bE[n0 + nbase + ni * 16 + (lane & 15)];

    int rb = row0 + mbase + ((lane >> 4) << 2);
#pragma unroll
    for (int mi = 0; mi < 4; mi++) {
        int t_[4]; float tp_[4]; int v_[4];
#pragma unroll
        for (int r = 0; r < 4; r++) {
            int gr = rb + mi * 16 + r;
            v_[r] = gr < cnt;
            int grc = v_[r] ? gr : (cnt - 1);
            t_[r] = permE[grc];
            tp_[r] = topp[t_[r]];
        }
#pragma unroll
        for (int ni = 0; ni < 4; ni++) {
            int col = n0 + nbase + ni * 16 + (lane & 15);
            f32x4 v = acc[mi][ni];
#pragma unroll
            for (int r = 0; r < 4; r++) {
                if (v_[r])
                    out[((size_t)t_[r] << 11) + col] = (v[r] + bv[ni]) * tp_[r];
            }
        }
    }
}

// ---------- kernel 4: aux loss ----------
__global__ void loss_kernel(const int* __restrict__ counts,
                            const float* __restrict__ sumt,
                            float* __restrict__ lossOut) {
    if (threadIdx.x == 0) {
        float acc = 0.0f;
        for (int e = 0; e < 8; e++) {
            float frac = (float)counts[e * 16] / 8192.0f;
            float prob = sumt[e * 16] / (8192.0f * 8192.0f);
            acc = fmaf(frac, prob, acc);
        }
        lossOut[0] = acc * 3e-6f * 8.0f;
    }
}

extern "C" void kernel_launch(void* const* d_in, const int* in_sizes, int n_in,
                              void* d_out, int out_size, void* d_ws, size_t ws_size,
                              hipStream_t stream) {
    const float* x  = (const float*)d_in[0];   // (4,2048,2048)
    const float* Wr = (const float*)d_in[1];   // (8,2048)
    const float* br = (const float*)d_in[2];   // (8,)
    const float* W  = (const float*)d_in[3];   // (8,2048,2048)
    const float* b  = (const float*)d_in[4];   // (8,2048)
    float* out = (float*)d_out;                // 16777216 y + 1 loss

    char* ws = (char*)d_ws;
    u16* Wb     = (u16*)ws;                      // 67,108,864 B
    u16* xb     = (u16*)(ws + 67108864);         // 33,554,432 B
    int* perm   = (int*)(ws + 100663296);        //    262,144 B (8 x 8192)
    float* topp = (float*)(ws + 100925440);      //     32,768 B
    int* counts = (int*)(ws + 100958208);        //        512 B (padded x16)
    float* sumt = (float*)(ws + 100958720);      //        512 B (padded x16)

    zero_kernel<<<1, 256, 0, stream>>>((u32*)counts);
    convert_w_kernel<<<(8 * 2048 * 2048) / (256 * 8), 256, 0, stream>>>(W, Wb);
    router_kernel<<<T_TOK / 4, 256, 0, stream>>>(x, Wr, br, xb, perm, topp, counts, sumt);
    moe_gemm_kernel<<<N_EXP * 64 * 16, 256, 0, stream>>>(xb, Wb, b, perm, counts, topp, out);
    loss_kernel<<<1, 64, 0, stream>>>(counts, sumt, out + (size_t)T_TOK * DMODEL);
}

// Round 3
// 412.188 us; speedup vs baseline: 1.5937x; 1.1887x over previous
//
#include <hip/hip_runtime.h>

typedef unsigned short u16;
typedef unsigned int u32;
typedef __attribute__((ext_vector_type(8))) __bf16 bf16x8;
typedef __attribute__((ext_vector_type(4))) float f32x4;

#define T_TOK 8192
#define DMODEL 2048
#define N_EXP 8
// counters padded: counts[e] at counts[e*16] (64 B apart), same for sumt

// ---------- helpers ----------
__device__ __forceinline__ u32 f2bf_bits(float f) {
    u32 u = __builtin_bit_cast(u32, f);
    return (u + 0x7fffu + ((u >> 16) & 1u)) >> 16;   // RNE truncate to bf16
}
__device__ __forceinline__ u32 pack2(float a, float b) {
    return f2bf_bits(a) | (f2bf_bits(b) << 16);
}

__device__ __forceinline__ void load_lds16(const u16* g, u16* l) {
    void* gnc = (void*)g;
    __builtin_amdgcn_global_load_lds(
        (__attribute__((address_space(1))) void*)gnc,
        (__attribute__((address_space(3))) void*)l,
        16, 0, 0);
}

// ---------- kernel 0: zero padded counters (counts 512B + sumt 512B) ----------
__global__ void zero_kernel(u32* p) {
    p[threadIdx.x] = 0u;   // 256 threads x 4B = 1024 B
}

// ---------- kernel 1: W fp32 -> bf16 ----------
__global__ void __launch_bounds__(256) convert_w_kernel(const float* __restrict__ W,
                                                        u16* __restrict__ Wb) {
    size_t i = ((size_t)blockIdx.x * 256 + threadIdx.x) * 8;
    float4 a = *(const float4*)(W + i);
    float4 b = *(const float4*)(W + i + 4);
    uint4 o;
    o.x = pack2(a.x, a.y);
    o.y = pack2(a.z, a.w);
    o.z = pack2(b.x, b.y);
    o.w = pack2(b.z, b.w);
    *(uint4*)(Wb + i) = o;
}

// ---------- kernel 2: router — 1 token/wave, 2048 blocks ----------
__global__ void __launch_bounds__(256) router_kernel(const float* __restrict__ x,
                                                     const float* __restrict__ Wr,
                                                     const float* __restrict__ br,
                                                     u16* __restrict__ xb,
                                                     int* __restrict__ perm,
                                                     float* __restrict__ topp,
                                                     int* __restrict__ counts,
                                                     float* __restrict__ sumt) {
    __shared__ int sEid[4];
    __shared__ float sTp[4];

    int tid = threadIdx.x;
    int lane = tid & 63;
    int w = tid >> 6;
    int t = blockIdx.x * 4 + w;

    const float4* xp = (const float4*)(x + ((size_t)t << 11));
    u16* xbp = xb + ((size_t)t << 11);

    float acc[8];
#pragma unroll
    for (int e = 0; e < 8; e++) acc[e] = 0.0f;

#pragma unroll
    for (int i = 0; i < 8; i++) {
        int vidx = i * 64 + lane;               // float4 index within the row
        float4 xv = xp[vidx];
        uint2 pk;
        pk.x = pack2(xv.x, xv.y);
        pk.y = pack2(xv.z, xv.w);
        *(uint2*)(xbp + (size_t)vidx * 4) = pk; // fused x -> bf16
#pragma unroll
        for (int e = 0; e < 8; e++) {
            float4 wv = *(const float4*)(Wr + e * DMODEL + vidx * 4);  // L2-resident
            acc[e] = fmaf(xv.x, wv.x, fmaf(xv.y, wv.y,
                      fmaf(xv.z, wv.z, fmaf(xv.w, wv.w, acc[e]))));
        }
    }
#pragma unroll
    for (int off = 32; off; off >>= 1)
#pragma unroll
        for (int e = 0; e < 8; e++)
            acc[e] += __shfl_xor(acc[e], off, 64);

    if (lane == 0) {
        float lg[8];
#pragma unroll
        for (int e = 0; e < 8; e++) lg[e] = acc[e] + br[e];
        float m = lg[0];
        int am = 0;
#pragma unroll
        for (int e = 1; e < 8; e++)
            if (lg[e] > m) { m = lg[e]; am = e; }
        float s = 0.0f;
#pragma unroll
        for (int e = 0; e < 8; e++) s += __expf(lg[e] - m);
        float tp = 1.0f / s;
        sEid[w] = am;
        sTp[w] = tp;
        topp[t] = tp;
    }
    __syncthreads();
    if (tid < 4) {
        int e = sEid[tid];
        float tp = sTp[tid];
        int pos = atomicAdd(&counts[e * 16], 1);          // padded: 8 separate lines
        perm[(e << 13) + pos] = blockIdx.x * 4 + tid;
        atomicAdd(&sumt[e * 16], tp);
    }
}

// ---------- kernel 3: grouped GEMM, BK=64, XOR-swizzled staging ----------
// LDS layout: slot(r, kc) = r*8 + (kc ^ (r&7)); slot s holds 16B chunk.
// Staging lane order == slot order (global_load_lds constraint); lane fetches
// global chunk c_g = (s&7) ^ (r&7) of row r -> 8 rows x 128B contiguous per
// wave-instruction (coalesced). Fragment ds_read_b128: bank = (kc^(m&7))*4,
// all 32 banks per 8 rows -> balanced.
// bid = tr*128 + e*16 + tc  -> active blocks are a contiguous prefix
__global__ void __launch_bounds__(256) moe_gemm_kernel(const u16* __restrict__ xb,
                                                       const u16* __restrict__ Wb,
                                                       const float* __restrict__ bias,
                                                       const int* __restrict__ perm,
                                                       const int* __restrict__ counts,
                                                       const float* __restrict__ topp,
                                                       float* __restrict__ out) {
    __shared__ __align__(16) u16 ldsA[8192];   // 128 rows x 64 k, swizzled, 16 KB
    __shared__ __align__(16) u16 ldsB[8192];

    int bid = blockIdx.x;
    int tr = bid >> 7;
    int e  = (bid >> 4) & 7;
    int tc = bid & 15;
    int cnt = counts[e * 16];
    int row0 = tr << 7;
    if (row0 >= cnt) return;
    int n0 = tc << 7;

    int tid = threadIdx.x;
    int lane = tid & 63;
    int w = tid >> 6;

    const int* permE = perm + (e << 13);
    const u16* WbE = Wb + ((size_t)e << 22);
    const u16* gA[4]; u16* lA[4];
    const u16* gB[4]; u16* lB[4];
#pragma unroll
    for (int j = 0; j < 4; j++) {
        int s = tid + j * 256;
        int r = s >> 3;                         // row 0..127
        int cg = (s & 7) ^ (r & 7);             // global chunk (xor-swizzled)
        int ta = permE[min(row0 + r, cnt - 1)];
        gA[j] = xb + ((size_t)ta << 11) + (cg << 3);
        gB[j] = WbE + ((size_t)(n0 + r) << 11) + (cg << 3);
        lA[j] = ldsA + s * 8;
        lB[j] = ldsB + s * 8;
    }

    // wave tiling: 2x2 waves of 64x64, each 4x4 grid of 16x16x32 MFMA
    int mbase = (w & 1) << 6;
    int nbase = (w >> 1) << 6;
    int mrow = lane & 15;
    int kq = lane >> 4;                         // 8-elem chunk within a 32-k subtile
    int s7 = mrow & 7;

    f32x4 acc[4][4];
#pragma unroll
    for (int mi = 0; mi < 4; mi++)
#pragma unroll
        for (int ni = 0; ni < 4; ni++)
            acc[mi][ni] = (f32x4){0.0f, 0.0f, 0.0f, 0.0f};

    for (int kt = 0; kt < DMODEL / 64; kt++) {
        int ko = kt << 6;
#pragma unroll
        for (int j = 0; j < 4; j++) load_lds16(gA[j] + ko, lA[j]);
#pragma unroll
        for (int j = 0; j < 4; j++) load_lds16(gB[j] + ko, lB[j]);
        __syncthreads();

#pragma unroll
        for (int ks = 0; ks < 2; ks++) {
            int kcs = (ks * 4 + kq) ^ s7;       // swizzled chunk column
            int aO = ((mbase + mrow) * 8 + kcs) * 8;   // u16 offset
            int bO = ((nbase + mrow) * 8 + kcs) * 8;
            bf16x8 af[4], bf[4];
#pragma unroll
            for (int i = 0; i < 4; i++) {
                af[i] = *(const bf16x8*)(ldsA + aO + i * 1024);  // +16 rows
                bf[i] = *(const bf16x8*)(ldsB + bO + i * 1024);
            }
#pragma unroll
            for (int mi = 0; mi < 4; mi++)
#pragma unroll
                for (int ni = 0; ni < 4; ni++)
                    acc[mi][ni] = __builtin_amdgcn_mfma_f32_16x16x32_bf16(
                        af[mi], bf[ni], acc[mi][ni], 0, 0, 0);
        }
        __syncthreads();
    }

    // epilogue: C/D layout col = lane&15 (n), row = (lane>>4)*4 + reg (m)
    const float* bE = bias + (e << 11);
    float bv[4];
#pragma unroll
    for (int ni = 0; ni < 4; ni++)
        bv[ni] = bE[n0 + nbase + ni * 16 + (lane & 15)];

    int rb = row0 + mbase + ((lane >> 4) << 2);
#pragma unroll
    for (int mi = 0; mi < 4; mi++) {
        int t_[4]; float tp_[4]; int v_[4];
#pragma unroll
        for (int r = 0; r < 4; r++) {
            int gr = rb + mi * 16 + r;
            v_[r] = gr < cnt;
            int grc = v_[r] ? gr : (cnt - 1);
            t_[r] = permE[grc];
            tp_[r] = topp[t_[r]];
        }
#pragma unroll
        for (int ni = 0; ni < 4; ni++) {
            int col = n0 + nbase + ni * 16 + (lane & 15);
            f32x4 v = acc[mi][ni];
#pragma unroll
            for (int r = 0; r < 4; r++) {
                if (v_[r])
                    out[((size_t)t_[r] << 11) + col] = (v[r] + bv[ni]) * tp_[r];
            }
        }
    }
}

// ---------- kernel 4: aux loss ----------
__global__ void loss_kernel(const int* __restrict__ counts,
                            const float* __restrict__ sumt,
                            float* __restrict__ lossOut) {
    if (threadIdx.x == 0) {
        float acc = 0.0f;
        for (int e = 0; e < 8; e++) {
            float frac = (float)counts[e * 16] / 8192.0f;
            float prob = sumt[e * 16] / (8192.0f * 8192.0f);
            acc = fmaf(frac, prob, acc);
        }
        lossOut[0] = acc * 3e-6f * 8.0f;
    }
}

extern "C" void kernel_launch(void* const* d_in, const int* in_sizes, int n_in,
                              void* d_out, int out_size, void* d_ws, size_t ws_size,
                              hipStream_t stream) {
    const float* x  = (const float*)d_in[0];   // (4,2048,2048)
    const float* Wr = (const float*)d_in[1];   // (8,2048)
    const float* br = (const float*)d_in[2];   // (8,)
    const float* W  = (const float*)d_in[3];   // (8,2048,2048)
    const float* b  = (const float*)d_in[4];   // (8,2048)
    float* out = (float*)d_out;                // 16777216 y + 1 loss

    char* ws = (char*)d_ws;
    u16* Wb     = (u16*)ws;                      // 67,108,864 B
    u16* xb     = (u16*)(ws + 67108864);         // 33,554,432 B
    int* perm   = (int*)(ws + 100663296);        //    262,144 B (8 x 8192)
    float* topp = (float*)(ws + 100925440);      //     32,768 B
    int* counts = (int*)(ws + 100958208);        //        512 B (padded x16)
    float* sumt = (float*)(ws + 100958720);      //        512 B (padded x16)

    zero_kernel<<<1, 256, 0, stream>>>((u32*)counts);
    convert_w_kernel<<<(8 * 2048 * 2048) / (256 * 8), 256, 0, stream>>>(W, Wb);
    router_kernel<<<T_TOK / 4, 256, 0, stream>>>(x, Wr, br, xb, perm, topp, counts, sumt);
    moe_gemm_kernel<<<N_EXP * 64 * 16, 256, 0, stream>>>(xb, Wb, b, perm, counts, topp, out);
    loss_kernel<<<1, 64, 0, stream>>>(counts, sumt, out + (size_t)T_TOK * DMODEL);
}

// Round 4
// 411.499 us; speedup vs baseline: 1.5964x; 1.0017x over previous
//
#include <hip/hip_runtime.h>

typedef unsigned short u16;
typedef unsigned int u32;
typedef __attribute__((ext_vector_type(8))) __bf16 bf16x8;
typedef __attribute__((ext_vector_type(4))) float f32x4;

#define T_TOK 8192
#define DMODEL 2048
#define N_EXP 8
// counters padded: counts[e] at counts[e*16] (64 B apart), same for sumt

// ---------- helpers ----------
__device__ __forceinline__ u32 f2bf_bits(float f) {
    u32 u = __builtin_bit_cast(u32, f);
    return (u + 0x7fffu + ((u >> 16) & 1u)) >> 16;   // RNE truncate to bf16
}
__device__ __forceinline__ u32 pack2(float a, float b) {
    return f2bf_bits(a) | (f2bf_bits(b) << 16);
}

__device__ __forceinline__ void load_lds16(const u16* g, u16* l) {
    void* gnc = (void*)g;
    __builtin_amdgcn_global_load_lds(
        (__attribute__((address_space(1))) void*)gnc,
        (__attribute__((address_space(3))) void*)l,
        16, 0, 0);
}

// ---------- kernel 0: zero padded counters (counts 512B + sumt 512B) ----------
__global__ void zero_kernel(u32* p) {
    p[threadIdx.x] = 0u;   // 256 threads x 4B = 1024 B
}

// ---------- kernel 1: W fp32 -> bf16 (BW-bound, 201 MB) ----------
__global__ void __launch_bounds__(256) convert_w_kernel(const float* __restrict__ W,
                                                        u16* __restrict__ Wb) {
    size_t i = ((size_t)blockIdx.x * 256 + threadIdx.x) * 8;
    float4 a = *(const float4*)(W + i);
    float4 b = *(const float4*)(W + i + 4);
    uint4 o;
    o.x = pack2(a.x, a.y);
    o.y = pack2(a.z, a.w);
    o.z = pack2(b.x, b.y);
    o.w = pack2(b.z, b.w);
    *(uint4*)(Wb + i) = o;
}

// ---------- kernel 2: router — 4 tokens/wave, Wr in registers per k-slice ----------
__global__ void __launch_bounds__(256) router_kernel(const float* __restrict__ x,
                                                     const float* __restrict__ Wr,
                                                     const float* __restrict__ br,
                                                     u16* __restrict__ xb,
                                                     int* __restrict__ perm,
                                                     float* __restrict__ topp,
                                                     int* __restrict__ counts,
                                                     float* __restrict__ sumt) {
    __shared__ int sEid[16];
    __shared__ float sTp[16];

    int tid = threadIdx.x;
    int lane = tid & 63;
    int w = tid >> 6;
    int t0 = blockIdx.x * 16 + w * 4;

    float acc[4][8];
#pragma unroll
    for (int tk = 0; tk < 4; tk++)
#pragma unroll
        for (int e = 0; e < 8; e++) acc[tk][e] = 0.0f;

#pragma unroll
    for (int i = 0; i < 8; i++) {
        int vidx = i * 64 + lane;               // float4 index within a row
        float4 wv[8];
#pragma unroll
        for (int e = 0; e < 8; e++)
            wv[e] = *(const float4*)(Wr + e * DMODEL + vidx * 4);   // L2-resident
#pragma unroll
        for (int tk = 0; tk < 4; tk++) {
            int t = t0 + tk;
            float4 xv = ((const float4*)(x + ((size_t)t << 11)))[vidx];
            uint2 pk;
            pk.x = pack2(xv.x, xv.y);
            pk.y = pack2(xv.z, xv.w);
            *(uint2*)(xb + ((size_t)t << 11) + (size_t)vidx * 4) = pk;
#pragma unroll
            for (int e = 0; e < 8; e++) {
                acc[tk][e] = fmaf(xv.x, wv[e].x, fmaf(xv.y, wv[e].y,
                              fmaf(xv.z, wv[e].z, fmaf(xv.w, wv[e].w, acc[tk][e]))));
            }
        }
    }
#pragma unroll
    for (int off = 32; off; off >>= 1)
#pragma unroll
        for (int tk = 0; tk < 4; tk++)
#pragma unroll
            for (int e = 0; e < 8; e++)
                acc[tk][e] += __shfl_xor(acc[tk][e], off, 64);

    if (lane == 0) {
#pragma unroll
        for (int tk = 0; tk < 4; tk++) {
            float lg[8];
#pragma unroll
            for (int e = 0; e < 8; e++) lg[e] = acc[tk][e] + br[e];
            float m = lg[0];
            int am = 0;
#pragma unroll
            for (int e = 1; e < 8; e++)
                if (lg[e] > m) { m = lg[e]; am = e; }
            float s = 0.0f;
#pragma unroll
            for (int e = 0; e < 8; e++) s += __expf(lg[e] - m);
            float tp = 1.0f / s;
            sEid[w * 4 + tk] = am;
            sTp[w * 4 + tk] = tp;
            topp[t0 + tk] = tp;
        }
    }
    __syncthreads();
    if (tid < 16) {
        int e = sEid[tid];
        float tp = sTp[tid];
        int pos = atomicAdd(&counts[e * 16], 1);          // padded: 8 separate lines
        perm[(e << 13) + pos] = blockIdx.x * 16 + tid;
        atomicAdd(&sumt[e * 16], tp);
    }
}

// ---------- kernel 3: grouped GEMM, BK=64, dbuf LDS, raw-barrier pipeline ----------
// bid = (tr*16 + tc)*8 + e  -> expert == bid%8 == XCD (round-robin heuristic):
// each XCD's L2 sees one expert's B slice (8 MB) + its A rows (~2 MB).
// K-loop: stage tile k+1, s_waitcnt vmcnt(8) (tile k done, k+1 still in
// flight), raw s_barrier, compute tile k, raw s_barrier (WAR protection).
__global__ void __launch_bounds__(256) moe_gemm_kernel(const u16* __restrict__ xb,
                                                       const u16* __restrict__ Wb,
                                                       const float* __restrict__ bias,
                                                       const int* __restrict__ perm,
                                                       const int* __restrict__ counts,
                                                       const float* __restrict__ topp,
                                                       float* __restrict__ out) {
    // [A buf0 | A buf1 | B buf0 | B buf1], each 8192 u16 = 16 KB; total 64 KB
    __shared__ __align__(16) u16 lds[32768];

    int bid = blockIdx.x;
    int e  = bid & 7;
    int tc = (bid >> 3) & 15;
    int tr = bid >> 7;
    int cnt = counts[e * 16];
    int row0 = tr << 7;
    if (row0 >= cnt) return;
    int n0 = tc << 7;

    int tid = threadIdx.x;
    int lane = tid & 63;
    int w = tid >> 6;

    // staging addresses: slot(r, kc) = r*8 + (kc ^ (r&7)); lane order == slot
    // order (global_load_lds constraint); global chunk cg = (s&7)^(r&7) keeps
    // each wave-instruction reading 8 rows x 128 B contiguous (coalesced).
    const int* permE = perm + (e << 13);
    const u16* WbE = Wb + ((size_t)e << 22);
    const u16* gA[4];
    const u16* gB[4];
    int sOff[4];
#pragma unroll
    for (int j = 0; j < 4; j++) {
        int s = tid + j * 256;
        int r = s >> 3;                         // row 0..127
        int cg = (s & 7) ^ (r & 7);             // global chunk (xor-swizzled)
        int ta = permE[min(row0 + r, cnt - 1)];
        gA[j] = xb + ((size_t)ta << 11) + (cg << 3);
        gB[j] = WbE + ((size_t)(n0 + r) << 11) + (cg << 3);
        sOff[j] = s * 8;
    }

    // wave tiling: 2x2 waves of 64x64, each 4x4 grid of 16x16x32 MFMA
    int mbase = (w & 1) << 6;
    int nbase = (w >> 1) << 6;
    int mrow = lane & 15;
    int kq = lane >> 4;                         // 8-elem chunk within 32-k subtile
    int s7 = mrow & 7;

    f32x4 acc[4][4];
#pragma unroll
    for (int mi = 0; mi < 4; mi++)
#pragma unroll
        for (int ni = 0; ni < 4; ni++)
            acc[mi][ni] = (f32x4){0.0f, 0.0f, 0.0f, 0.0f};

    // prologue: stage tile 0 into buf 0
#pragma unroll
    for (int j = 0; j < 4; j++) load_lds16(gA[j], lds + sOff[j]);
#pragma unroll
    for (int j = 0; j < 4; j++) load_lds16(gB[j], lds + 16384 + sOff[j]);

    for (int kt = 0; kt < 32; kt++) {
        int p = kt & 1;
        if (kt < 31) {                          // stage tile kt+1 into buf p^1
            int ko = (kt + 1) << 6;
            u16* la = lds + (p ^ 1) * 8192;
            u16* lb = lds + 16384 + (p ^ 1) * 8192;
#pragma unroll
            for (int j = 0; j < 4; j++) load_lds16(gA[j] + ko, la + sOff[j]);
#pragma unroll
            for (int j = 0; j < 4; j++) load_lds16(gB[j] + ko, lb + sOff[j]);
            asm volatile("s_waitcnt vmcnt(8)" ::: "memory");   // tile kt landed
        } else {
            asm volatile("s_waitcnt vmcnt(0)" ::: "memory");
        }
        asm volatile("s_barrier" ::: "memory"); // all waves' tile-kt loads done

        const u16* bufA = lds + p * 8192;
        const u16* bufB = lds + 16384 + p * 8192;
#pragma unroll
        for (int ks = 0; ks < 2; ks++) {
            int kcs = (ks * 4 + kq) ^ s7;       // swizzled chunk column
            int aO = ((mbase + mrow) * 8 + kcs) * 8;   // u16 offset
            int bO = ((nbase + mrow) * 8 + kcs) * 8;
            bf16x8 af[4], bf[4];
#pragma unroll
            for (int i = 0; i < 4; i++) {
                af[i] = *(const bf16x8*)(bufA + aO + i * 1024);  // +16 rows
                bf[i] = *(const bf16x8*)(bufB + bO + i * 1024);
            }
#pragma unroll
            for (int mi = 0; mi < 4; mi++)
#pragma unroll
                for (int ni = 0; ni < 4; ni++)
                    acc[mi][ni] = __builtin_amdgcn_mfma_f32_16x16x32_bf16(
                        af[mi], bf[ni], acc[mi][ni], 0, 0, 0);
        }
        asm volatile("s_barrier" ::: "memory"); // consumption done before overwrite
    }

    // epilogue: C/D layout col = lane&15 (n), row = (lane>>4)*4 + reg (m)
    const float* bE = bias + (e << 11);
    float bv[4];
#pragma unroll
    for (int ni = 0; ni < 4; ni++)
        bv[ni] = bE[n0 + nbase + ni * 16 + (lane & 15)];

    int rb = row0 + mbase + ((lane >> 4) << 2);
#pragma unroll
    for (int mi = 0; mi < 4; mi++) {
        int t_[4]; float tp_[4]; int v_[4];
#pragma unroll
        for (int r = 0; r < 4; r++) {
            int gr = rb + mi * 16 + r;
            v_[r] = gr < cnt;
            int grc = v_[r] ? gr : (cnt - 1);
            t_[r] = permE[grc];
            tp_[r] = topp[t_[r]];
        }
#pragma unroll
        for (int ni = 0; ni < 4; ni++) {
            int col = n0 + nbase + ni * 16 + (lane & 15);
            f32x4 v = acc[mi][ni];
#pragma unroll
            for (int r = 0; r < 4; r++) {
                if (v_[r])
                    out[((size_t)t_[r] << 11) + col] = (v[r] + bv[ni]) * tp_[r];
            }
        }
    }
}

// ---------- kernel 4: aux loss ----------
__global__ void loss_kernel(const int* __restrict__ counts,
                            const float* __restrict__ sumt,
                            float* __restrict__ lossOut) {
    if (threadIdx.x == 0) {
        float acc = 0.0f;
        for (int e = 0; e < 8; e++) {
            float frac = (float)counts[e * 16] / 8192.0f;
            float prob = sumt[e * 16] / (8192.0f * 8192.0f);
            acc = fmaf(frac, prob, acc);
        }
        lossOut[0] = acc * 3e-6f * 8.0f;
    }
}

extern "C" void kernel_launch(void* const* d_in, const int* in_sizes, int n_in,
                              void* d_out, int out_size, void* d_ws, size_t ws_size,
                              hipStream_t stream) {
    const float* x  = (const float*)d_in[0];   // (4,2048,2048)
    const float* Wr = (const float*)d_in[1];   // (8,2048)
    const float* br = (const float*)d_in[2];   // (8,)
    const float* W  = (const float*)d_in[3];   // (8,2048,2048)
    const float* b  = (const float*)d_in[4];   // (8,2048)
    float* out = (float*)d_out;                // 16777216 y + 1 loss

    char* ws = (char*)d_ws;
    u16* Wb     = (u16*)ws;                      // 67,108,864 B
    u16* xb     = (u16*)(ws + 67108864);         // 33,554,432 B
    int* perm   = (int*)(ws + 100663296);        //    262,144 B (8 x 8192)
    float* topp = (float*)(ws + 100925440);      //     32,768 B
    int* counts = (int*)(ws + 100958208);        //        512 B (padded x16)
    float* sumt = (float*)(ws + 100958720);      //        512 B (padded x16)

    zero_kernel<<<1, 256, 0, stream>>>((u32*)counts);
    convert_w_kernel<<<(8 * 2048 * 2048) / (256 * 8), 256, 0, stream>>>(W, Wb);
    router_kernel<<<T_TOK / 16, 256, 0, stream>>>(x, Wr, br, xb, perm, topp, counts, sumt);
    moe_gemm_kernel<<<N_EXP * 64 * 16, 256, 0, stream>>>(xb, Wb, b, perm, counts, topp, out);
    loss_kernel<<<1, 64, 0, stream>>>(counts, sumt, out + (size_t)T_TOK * DMODEL);
}